// Round 2
// baseline (120.298 us; speedup 1.0000x reference)
//
#include <hip/hip_runtime.h>
#include <hip/hip_cooperative_groups.h>
#include <float.h>

namespace cg = cooperative_groups;

#define INPUT_DIM 2304
#define SUB_DIM 64
#define ATOMS 512
#define NUM_EXPERTS 256
#define TOPK 4

// offset = 1/sqrt(2304) = 1/48 exactly
#define OFFSET (1.0f / 48.0f)

__global__ void __launch_bounds__(256, 1) moe_fused(
    const float* __restrict__ x,
    const float* __restrict__ enc_top,
    const float* __restrict__ W_down,
    const float* __restrict__ enc_w,
    float* __restrict__ out,
    float* __restrict__ ws)
{
    cg::grid_group grid = cg::this_grid();

    // workspace layout (floats)
    float* codes = ws;            // 256
    float* val   = ws + 256;      // 4
    float* sub   = ws + 260;      // 256
    float* dec   = ws + 516;      // 256
    int*   idx   = (int*)(ws + 772); // 4

    __shared__ float s_red[256];
    __shared__ float s_a[512];      // sec (phase 4) / sdec (phase 5)
    __shared__ float s_b[SUB_DIM];  // ssub (phase 4)
    __shared__ int   s_idx[TOPK];
    __shared__ float s_val[TOPK];

    const int b    = blockIdx.x;
    const int t    = threadIdx.x;
    const int lane = t & 63;
    const int wave = t >> 6;

    // ---------------- Phase 1: codes[b] = relu_off(enc_top[b] . x) ----------------
    {
        const float* row = enc_top + (size_t)b * INPUT_DIM;
        float acc = 0.0f;
        #pragma unroll
        for (int i = 0; i < INPUT_DIM / 256; ++i)
            acc += row[t + i * 256] * x[t + i * 256];
        #pragma unroll
        for (int o = 32; o > 0; o >>= 1) acc += __shfl_down(acc, o);
        if (lane == 0) s_red[wave] = acc;
        __syncthreads();
        if (t == 0) {
            float s = s_red[0] + s_red[1] + s_red[2] + s_red[3];
            codes[b] = (s >= OFFSET) ? s : 0.0f;
        }
    }
    grid.sync();

    // ---------------- Phase 2: top-4 of 256 codes (block 0, wave 0) ----------------
    if (b == 0 && wave == 0) {
        float v[4];
        int   id[4];
        #pragma unroll
        for (int i = 0; i < 4; ++i) { id[i] = lane + 64 * i; v[i] = codes[id[i]]; }
        for (int k = 0; k < TOPK; ++k) {
            float bv = v[0]; int bi = id[0];
            #pragma unroll
            for (int i = 1; i < 4; ++i)
                if (v[i] > bv || (v[i] == bv && id[i] < bi)) { bv = v[i]; bi = id[i]; }
            #pragma unroll
            for (int o = 32; o > 0; o >>= 1) {
                float ov = __shfl_down(bv, o);
                int   oi = __shfl_down(bi, o);
                if (ov > bv || (ov == bv && oi < bi)) { bv = ov; bi = oi; }
            }
            bv = __shfl(bv, 0);
            bi = __shfl(bi, 0);
            if (lane == 0) { idx[k] = bi; val[k] = bv; }
            #pragma unroll
            for (int i = 0; i < 4; ++i)
                if (id[i] == bi) v[i] = -FLT_MAX;
        }
    }
    grid.sync();

    // ---------------- Phase 3: sub[e][s] = W_down[idx[e]][s] . x ----------------
    {
        const int e = b >> 6, s = b & 63;
        const int E = idx[e];
        const float* row = W_down + ((size_t)E * SUB_DIM + s) * INPUT_DIM;
        float acc = 0.0f;
        #pragma unroll
        for (int i = 0; i < INPUT_DIM / 256; ++i)
            acc += row[t + i * 256] * x[t + i * 256];
        #pragma unroll
        for (int o = 32; o > 0; o >>= 1) acc += __shfl_down(acc, o);
        if (lane == 0) s_red[wave] = acc;
        __syncthreads();
        if (t == 0) sub[b] = s_red[0] + s_red[1] + s_red[2] + s_red[3];
    }
    grid.sync();

    // ---------------- Phase 4: per-expert encode+decode (blocks 0..3) ----------------
    if (b < TOPK) {
        const int E = idx[b];
        if (t < SUB_DIM) s_b[t] = sub[b * SUB_DIM + t];
        __syncthreads();
        const float* W = enc_w + (size_t)E * ATOMS * SUB_DIM;
        #pragma unroll
        for (int r = 0; r < ATOMS / 256; ++r) {
            int a = t + r * 256;
            const float4* row4 = (const float4*)(W + (size_t)a * SUB_DIM);
            float acc = 0.0f;
            #pragma unroll
            for (int i = 0; i < SUB_DIM / 4; ++i) {
                float4 w = row4[i];
                acc += w.x * s_b[4*i] + w.y * s_b[4*i+1] + w.z * s_b[4*i+2] + w.w * s_b[4*i+3];
            }
            s_a[a] = (acc >= OFFSET) ? acc : 0.01f * acc;  // leaky, slope .01
        }
        __syncthreads();
        // dec[b][s] = sum_a W[a][s] * ec[a]
        {
            const int s = lane, g = wave;
            float acc = 0.0f;
            for (int a = g * 128; a < (g + 1) * 128; ++a)
                acc += W[(size_t)a * SUB_DIM + s] * s_a[a];
            s_red[t] = acc;
            __syncthreads();
            if (t < SUB_DIM)
                dec[b * SUB_DIM + s] = s_red[s] + s_red[s + 64] + s_red[s + 128] + s_red[s + 192];
        }
    }
    grid.sync();

    // ---------------- Phase 5: recon (blocks 0..35, 64 d-positions each) ----------------
    if (b < INPUT_DIM / SUB_DIM) {  // 36 blocks
        s_a[t] = dec[t];            // 256 = TOPK*SUB_DIM
        if (t < TOPK) { s_idx[t] = idx[t]; s_val[t] = val[t]; }
        __syncthreads();
        const int d = b * 64 + lane;
        const int e = wave;         // one expert per wave
        const int E = s_idx[e];
        float acc = s_val[e] * enc_top[(size_t)E * INPUT_DIM + d];
        const float* W = W_down + (size_t)E * SUB_DIM * INPUT_DIM + d;
        #pragma unroll
        for (int s = 0; s < SUB_DIM; ++s)
            acc += W[(size_t)s * INPUT_DIM] * s_a[e * SUB_DIM + s];
        s_red[t] = acc;
        __syncthreads();
        if (t < 64) out[d] = s_red[t] + s_red[t + 64] + s_red[t + 128] + s_red[t + 192];
    }
}

extern "C" void kernel_launch(void* const* d_in, const int* in_sizes, int n_in,
                              void* d_out, int out_size, void* d_ws, size_t ws_size,
                              hipStream_t stream) {
    const float* x       = (const float*)d_in[0];
    const float* enc_top = (const float*)d_in[1];
    const float* W_down  = (const float*)d_in[2];
    const float* enc_w   = (const float*)d_in[3];
    float* out = (float*)d_out;
    float* ws  = (float*)d_ws;

    void* args[] = { (void*)&x, (void*)&enc_top, (void*)&W_down, (void*)&enc_w,
                     (void*)&out, (void*)&ws };
    hipLaunchCooperativeKernel((const void*)moe_fused, dim3(NUM_EXPERTS), dim3(256),
                               args, 0, stream);
}

// Round 3
// 113.974 us; speedup vs baseline: 1.0555x; 1.0555x over previous
//
#include <hip/hip_runtime.h>
#include <hip/hip_cooperative_groups.h>
#include <float.h>

#define INPUT_DIM 2304
#define SUB_DIM 64
#define ATOMS 512
#define NUM_EXPERTS 256
#define TOPK 4

// offset = 1/sqrt(2304) = 1/48 exactly
#define OFFSET (1.0f / 48.0f)

// Flags live in ws at byte offset 4096; zeroed by hipMemsetAsync every call.
struct Flags {
    unsigned int cnt_codes;       // -> 256
    unsigned int flg_topk;        // -> 1
    unsigned int cnt_sub[TOPK];   // -> 64 each
    unsigned int cnt_exp;         // -> 4
};

__device__ __forceinline__ void spin_ge(const unsigned int* p, unsigned int tgt) {
    while (__hip_atomic_load(p, __ATOMIC_ACQUIRE, __HIP_MEMORY_SCOPE_AGENT) < tgt)
        __builtin_amdgcn_s_sleep(1);
}

__device__ __forceinline__ void release_add(unsigned int* p) {
    __hip_atomic_fetch_add(p, 1u, __ATOMIC_RELEASE, __HIP_MEMORY_SCOPE_AGENT);
}

__global__ void __launch_bounds__(256, 1) moe_fused(
    const float* __restrict__ x,
    const float* __restrict__ enc_top,
    const float* __restrict__ W_down,
    const float* __restrict__ enc_w,
    float* __restrict__ out,
    float* __restrict__ ws)
{
    float* codes = ws;               // 256
    float* val   = ws + 256;         // 4
    float* sub   = ws + 260;         // 256
    float* dec   = ws + 516;         // 256
    int*   idx   = (int*)(ws + 772); // 4
    Flags* fl    = (Flags*)((char*)ws + 4096);

    __shared__ float s_red[256];
    __shared__ float s_ec[ATOMS];    // sec (P4) / sdec in [0..255] (P5)
    __shared__ float s_sub[SUB_DIM];

    const int b    = blockIdx.x;
    const int t    = threadIdx.x;
    const int lane = t & 63;
    const int wave = t >> 6;

    // ---------------- P1: codes[b] = relu_off(enc_top[b] . x) ----------------
    {
        const float* row = enc_top + (size_t)b * INPUT_DIM;
        float acc = 0.0f;
        #pragma unroll
        for (int i = 0; i < INPUT_DIM / 256; ++i)
            acc += row[t + i * 256] * x[t + i * 256];
        #pragma unroll
        for (int o = 32; o > 0; o >>= 1) acc += __shfl_down(acc, o);
        if (lane == 0) s_red[wave] = acc;
        __syncthreads();
        if (t == 0) {
            float s = s_red[0] + s_red[1] + s_red[2] + s_red[3];
            codes[b] = (s >= OFFSET) ? s : 0.0f;
            release_add(&fl->cnt_codes);
        }
    }

    // ---------------- P2: top-4 (block 0, wave 0 only; no block barrier) ----------------
    if (b == 0 && wave == 0) {
        spin_ge(&fl->cnt_codes, NUM_EXPERTS);
        float v[4]; int id[4];
        #pragma unroll
        for (int i = 0; i < 4; ++i) { id[i] = lane + 64 * i; v[i] = codes[id[i]]; }
        for (int k = 0; k < TOPK; ++k) {
            float bv = v[0]; int bi = id[0];
            #pragma unroll
            for (int i = 1; i < 4; ++i)
                if (v[i] > bv || (v[i] == bv && id[i] < bi)) { bv = v[i]; bi = id[i]; }
            #pragma unroll
            for (int o = 32; o > 0; o >>= 1) {
                float ov = __shfl_down(bv, o);
                int   oi = __shfl_down(bi, o);
                if (ov > bv || (ov == bv && oi < bi)) { bv = ov; bi = oi; }
            }
            bv = __shfl(bv, 0);
            bi = __shfl(bi, 0);
            if (lane == 0) { idx[k] = bi; val[k] = bv; }
            #pragma unroll
            for (int i = 0; i < 4; ++i)
                if (id[i] == bi) v[i] = -FLT_MAX;
        }
        if (lane == 0)
            __hip_atomic_store(&fl->flg_topk, 1u, __ATOMIC_RELEASE, __HIP_MEMORY_SCOPE_AGENT);
    }

    // ---------------- P3: sub[b] = W_down[idx[b>>6]][b&63] . x ----------------
    {
        spin_ge(&fl->flg_topk, 1u);  // every thread acquires -> its later reads see idx
        const int e = b >> 6;
        const int E = idx[e];
        const int s = b & 63;
        const float* row = W_down + ((size_t)E * SUB_DIM + s) * INPUT_DIM;
        float acc = 0.0f;
        #pragma unroll
        for (int i = 0; i < INPUT_DIM / 256; ++i)
            acc += row[t + i * 256] * x[t + i * 256];
        #pragma unroll
        for (int o = 32; o > 0; o >>= 1) acc += __shfl_down(acc, o);
        if (lane == 0) s_red[wave] = acc;
        __syncthreads();
        if (t == 0) {
            sub[b] = s_red[0] + s_red[1] + s_red[2] + s_red[3];
            release_add(&fl->cnt_sub[e]);
        }
    }

    // ---------------- P4: expert encode+decode (blocks 0..3) ----------------
    if (b < TOPK) {
        spin_ge(&fl->cnt_sub[b], SUB_DIM);
        const int E = idx[b];
        if (t < SUB_DIM) s_sub[t] = sub[b * SUB_DIM + t];
        __syncthreads();
        const float* W = enc_w + (size_t)E * ATOMS * SUB_DIM;
        #pragma unroll
        for (int r = 0; r < ATOMS / 256; ++r) {
            int a = t + r * 256;
            const float4* row4 = (const float4*)(W + (size_t)a * SUB_DIM);
            float acc = 0.0f;
            #pragma unroll
            for (int i = 0; i < SUB_DIM / 4; ++i) {
                float4 w = row4[i];
                acc += w.x * s_sub[4*i] + w.y * s_sub[4*i+1] + w.z * s_sub[4*i+2] + w.w * s_sub[4*i+3];
            }
            s_ec[a] = (acc >= OFFSET) ? acc : 0.01f * acc;   // leaky slope .01
        }
        __syncthreads();
        {
            float acc = 0.0f;
            for (int a = wave * 128; a < (wave + 1) * 128; ++a)
                acc += W[(size_t)a * SUB_DIM + lane] * s_ec[a];
            s_red[t] = acc;
            __syncthreads();
            if (t < SUB_DIM)
                dec[b * SUB_DIM + t] = s_red[t] + s_red[t + 64] + s_red[t + 128] + s_red[t + 192];
            __syncthreads();
            if (t == 0) release_add(&fl->cnt_exp);
        }
    }

    // ---------------- P5: recon (blocks 0..35) ----------------
    if (b < INPUT_DIM / SUB_DIM) {
        spin_ge(&fl->cnt_exp, TOPK);   // all threads acquire
        s_ec[t] = dec[t];              // 256 == TOPK*SUB_DIM (reuse LDS as sdec)
        __syncthreads();
        const int d = b * 64 + lane;
        const int e = wave;
        const int E = idx[e];
        float acc = val[e] * enc_top[(size_t)E * INPUT_DIM + d];
        const float* W = W_down + (size_t)E * SUB_DIM * INPUT_DIM + d;
        #pragma unroll
        for (int s = 0; s < SUB_DIM; ++s)
            acc += W[(size_t)s * INPUT_DIM] * s_ec[e * SUB_DIM + s];
        s_red[t] = acc;
        __syncthreads();
        if (t < 64) out[d] = s_red[t] + s_red[t + 64] + s_red[t + 128] + s_red[t + 192];
    }
}

extern "C" void kernel_launch(void* const* d_in, const int* in_sizes, int n_in,
                              void* d_out, int out_size, void* d_ws, size_t ws_size,
                              hipStream_t stream) {
    const float* x       = (const float*)d_in[0];
    const float* enc_top = (const float*)d_in[1];
    const float* W_down  = (const float*)d_in[2];
    const float* enc_w   = (const float*)d_in[3];
    float* out = (float*)d_out;
    float* ws  = (float*)d_ws;

    // zero the flag block (ws is NOT re-poisoned between replays -> must reset)
    hipMemsetAsync((char*)d_ws + 4096, 0, sizeof(Flags), stream);

    void* args[] = { (void*)&x, (void*)&enc_top, (void*)&W_down, (void*)&enc_w,
                     (void*)&out, (void*)&ws };
    hipLaunchCooperativeKernel((const void*)moe_fused, dim3(NUM_EXPERTS), dim3(256),
                               args, 0, stream);
}

// Round 4
// 47.317 us; speedup vs baseline: 2.5424x; 2.4087x over previous
//
#include <hip/hip_runtime.h>
#include <hip/hip_cooperative_groups.h>
#include <float.h>

#define INPUT_DIM 2304
#define SUB_DIM 64
#define ATOMS 512
#define NUM_EXPERTS 256
#define TOPK 4
#define NBLK 64

// offset = 1/sqrt(2304) = 1/48 exactly
#define OFFSET (1.0f / 48.0f)

// ---- flag plumbing: store+poll, one flag per 64B line, no RMW ----
#define FLAG_STRIDE 16           // u32s -> 64 bytes
#define FLAGS_OFF 4096           // byte offset in ws
// fcode[64] | fsub[64] | ftop | fexp[4]  (each slot 64B)
#define FLAGS_BYTES ((NBLK + NBLK + 1 + TOPK) * 64)

__device__ __forceinline__ unsigned int flag_ld(const unsigned int* p) {
    return __hip_atomic_load(p, __ATOMIC_RELAXED, __HIP_MEMORY_SCOPE_AGENT);
}
__device__ __forceinline__ void flag_st(unsigned int* p) {
    __hip_atomic_store(p, 1u, __ATOMIC_RELAXED, __HIP_MEMORY_SCOPE_AGENT);
}
__device__ __forceinline__ void fence_rel() {
    __builtin_amdgcn_fence(__ATOMIC_RELEASE, "agent");
}
__device__ __forceinline__ void fence_acq() {
    __builtin_amdgcn_fence(__ATOMIC_ACQUIRE, "agent");
}

__global__ void __launch_bounds__(256, 1) moe_fused(
    const float* __restrict__ x,
    const float* __restrict__ enc_top,
    const float* __restrict__ W_down,
    const float* __restrict__ enc_w,
    float* __restrict__ out,
    float* __restrict__ ws)
{
    float* codes = ws;               // 256
    float* val   = ws + 256;         // 4
    float* sub   = ws + 260;         // 256
    float* dec   = ws + 516;         // 256
    int*   idx   = (int*)(ws + 772); // 4

    unsigned int* flags = (unsigned int*)((char*)ws + FLAGS_OFF);
    unsigned int* fcode = flags;                        // [64] x stride16
    unsigned int* fsub  = flags + NBLK * FLAG_STRIDE;   // [64] x stride16
    unsigned int* ftop  = flags + 2 * NBLK * FLAG_STRIDE;          // single
    unsigned int* fexp  = ftop + FLAG_STRIDE;           // [4] x stride16

    __shared__ float s_red[256];
    __shared__ float s_ec[ATOMS];    // sec (P4) / sdec (P5)
    __shared__ float s_sub[SUB_DIM];

    const int b    = blockIdx.x;     // 0..63
    const int t    = threadIdx.x;    // 0..255
    const int lane = t & 63;
    const int wave = t >> 6;

    // ---------------- P1: codes (one row per wave; 64 blocks x 4 waves = 256 rows) ----
    {
        const int c = b * 4 + wave;
        const float* row = enc_top + (size_t)c * INPUT_DIM;
        float acc = 0.0f;
        #pragma unroll
        for (int i = 0; i < INPUT_DIM / 64; ++i)
            acc += row[lane + i * 64] * x[lane + i * 64];
        #pragma unroll
        for (int o = 32; o > 0; o >>= 1) acc += __shfl_down(acc, o);
        if (lane == 0) codes[c] = (acc >= OFFSET) ? acc : 0.0f;
        __syncthreads();                 // drains vmem (compiler waitcnt) per block
        if (t == 0) { fence_rel(); flag_st(&fcode[b * FLAG_STRIDE]); }
    }

    // ---------------- P2: top-4 (block 0, wave 0) ----------------
    if (b == 0 && wave == 0) {
        while (!__all(flag_ld(&fcode[lane * FLAG_STRIDE]) != 0))
            __builtin_amdgcn_s_sleep(1);
        fence_acq();
        float v[4]; int id[4];
        #pragma unroll
        for (int i = 0; i < 4; ++i) { id[i] = lane + 64 * i; v[i] = codes[id[i]]; }
        for (int k = 0; k < TOPK; ++k) {
            float bv = v[0]; int bi = id[0];
            #pragma unroll
            for (int i = 1; i < 4; ++i)
                if (v[i] > bv || (v[i] == bv && id[i] < bi)) { bv = v[i]; bi = id[i]; }
            #pragma unroll
            for (int o = 32; o > 0; o >>= 1) {
                float ov = __shfl_down(bv, o);
                int   oi = __shfl_down(bi, o);
                if (ov > bv || (ov == bv && oi < bi)) { bv = ov; bi = oi; }
            }
            bv = __shfl(bv, 0);
            bi = __shfl(bi, 0);
            if (lane == 0) { idx[k] = bi; val[k] = bv; }
            #pragma unroll
            for (int i = 0; i < 4; ++i)
                if (id[i] == bi) v[i] = -FLT_MAX;
        }
        if (lane == 0) { fence_rel(); flag_st(ftop); }
    }

    // ---------------- P3: sub (one row per wave; rows r = 4b+wave) ----------------
    {
        if (wave == 0) {
            while (flag_ld(ftop) == 0) __builtin_amdgcn_s_sleep(1);
            fence_acq();
        }
        __syncthreads();
        const int r = b * 4 + wave;          // 0..255
        const int e = r >> 6;                // 0..3
        const int E = idx[e];
        const int s = r & 63;
        const float* row = W_down + ((size_t)E * SUB_DIM + s) * INPUT_DIM;
        float acc = 0.0f;
        #pragma unroll
        for (int i = 0; i < INPUT_DIM / 64; ++i)
            acc += row[lane + i * 64] * x[lane + i * 64];
        #pragma unroll
        for (int o = 32; o > 0; o >>= 1) acc += __shfl_down(acc, o);
        if (lane == 0) sub[r] = acc;
        __syncthreads();
        if (t == 0) { fence_rel(); flag_st(&fsub[b * FLAG_STRIDE]); }
    }

    // ---------------- P4: expert encode+decode (blocks 0..3) ----------------
    if (b < TOPK) {
        if (wave == 0) {
            // expert b's sub rows were produced by blocks 16b .. 16b+15
            while (!__all(lane < 16 ? (flag_ld(&fsub[(b * 16 + lane) * FLAG_STRIDE]) != 0) : 1))
                __builtin_amdgcn_s_sleep(1);
            fence_acq();
        }
        __syncthreads();
        const int E = idx[b];
        if (t < SUB_DIM) s_sub[t] = sub[b * SUB_DIM + t];
        __syncthreads();
        const float* W = enc_w + (size_t)E * ATOMS * SUB_DIM;
        #pragma unroll
        for (int r = 0; r < ATOMS / 256; ++r) {
            int a = t + r * 256;
            const float4* row4 = (const float4*)(W + (size_t)a * SUB_DIM);
            float acc = 0.0f;
            #pragma unroll
            for (int i = 0; i < SUB_DIM / 4; ++i) {
                float4 w = row4[i];
                acc += w.x * s_sub[4*i] + w.y * s_sub[4*i+1] + w.z * s_sub[4*i+2] + w.w * s_sub[4*i+3];
            }
            s_ec[a] = (acc >= OFFSET) ? acc : 0.01f * acc;   // leaky slope .01
        }
        __syncthreads();
        {
            float acc = 0.0f;
            for (int a = wave * 128; a < (wave + 1) * 128; ++a)
                acc += W[(size_t)a * SUB_DIM + lane] * s_ec[a];
            s_red[t] = acc;
            __syncthreads();
            if (t < SUB_DIM)
                dec[b * SUB_DIM + t] = s_red[t] + s_red[t + 64] + s_red[t + 128] + s_red[t + 192];
            __syncthreads();
            if (t == 0) { fence_rel(); flag_st(&fexp[b * FLAG_STRIDE]); }
        }
    }

    // ---------------- P5: recon (blocks 0..35) ----------------
    if (b < INPUT_DIM / SUB_DIM) {
        if (wave == 0) {
            while (!__all(lane < TOPK ? (flag_ld(&fexp[lane * FLAG_STRIDE]) != 0) : 1))
                __builtin_amdgcn_s_sleep(1);
            fence_acq();
        }
        __syncthreads();
        s_ec[t] = dec[t];                // 256 == TOPK*SUB_DIM
        __syncthreads();
        const int d = b * 64 + lane;
        const int e = wave;
        const int E = idx[e];
        float acc = val[e] * enc_top[(size_t)E * INPUT_DIM + d];
        const float* W = W_down + (size_t)E * SUB_DIM * INPUT_DIM + d;
        #pragma unroll
        for (int s = 0; s < SUB_DIM; ++s)
            acc += W[(size_t)s * INPUT_DIM] * s_ec[e * SUB_DIM + s];
        s_red[t] = acc;
        __syncthreads();
        if (t < 64) out[d] = s_red[t] + s_red[t + 64] + s_red[t + 128] + s_red[t + 192];
    }
}

extern "C" void kernel_launch(void* const* d_in, const int* in_sizes, int n_in,
                              void* d_out, int out_size, void* d_ws, size_t ws_size,
                              hipStream_t stream) {
    const float* x       = (const float*)d_in[0];
    const float* enc_top = (const float*)d_in[1];
    const float* W_down  = (const float*)d_in[2];
    const float* enc_w   = (const float*)d_in[3];
    float* out = (float*)d_out;
    float* ws  = (float*)d_ws;

    // reset flags every call (ws is NOT re-poisoned between replays)
    hipMemsetAsync((char*)d_ws + FLAGS_OFF, 0, FLAGS_BYTES, stream);

    void* args[] = { (void*)&x, (void*)&enc_top, (void*)&W_down, (void*)&enc_w,
                     (void*)&out, (void*)&ws };
    hipLaunchCooperativeKernel((const void*)moe_fused, dim3(NBLK), dim3(256),
                               args, 0, stream);
}

// Round 5
// 24.052 us; speedup vs baseline: 5.0016x; 1.9673x over previous
//
#include <hip/hip_runtime.h>
#include <float.h>

#define INPUT_DIM 2304
#define SUB_DIM 64
#define ATOMS 512
#define NUM_EXPERTS 256
#define TOPK 4
#define NBLK 64

// offset = 1/sqrt(2304) = 1/48 exactly
#define OFFSET (1.0f / 48.0f)
#define MAGIC 0x9E3779B9u

// ---- fence-free sync primitives: relaxed agent atomics -> sc1 (coherence point = L3) ----
__device__ __forceinline__ unsigned int flag_ld(const unsigned int* p) {
    return __hip_atomic_load(p, __ATOMIC_RELAXED, __HIP_MEMORY_SCOPE_AGENT);
}
__device__ __forceinline__ void flag_st(unsigned int* p, unsigned int v) {
    __hip_atomic_store(p, v, __ATOMIC_RELAXED, __HIP_MEMORY_SCOPE_AGENT);
}
__device__ __forceinline__ float gldf(const float* p) {
    return __hip_atomic_load(p, __ATOMIC_RELAXED, __HIP_MEMORY_SCOPE_AGENT);
}
__device__ __forceinline__ void gstf(float* p, float v) {
    __hip_atomic_store(p, v, __ATOMIC_RELAXED, __HIP_MEMORY_SCOPE_AGENT);
}

// ws float layout: codes[256] @0 | sub[256] @256 | dec[256] @512
// flags (u32) @byte 4096: fcode[64][64] | fsub[32] | fexp[36][4]
// Protocol: producer stores MAGIC; single reader polls ==MAGIC then resets to 0.
// Works for any initial garbage (poison 0xAAAAAAAA != MAGIC) with no memset.

__global__ void __launch_bounds__(256, 1) moe_fused(
    const float* __restrict__ x,
    const float* __restrict__ enc_top,
    const float* __restrict__ W_down,
    const float* __restrict__ enc_w,
    float* __restrict__ out,
    float* __restrict__ ws)
{
    float* codes = ws;          // 256
    float* sub   = ws + 256;    // 256
    float* dec   = ws + 512;    // 256
    unsigned int* fl    = (unsigned int*)((char*)ws + 4096);
    unsigned int* fcode = fl;                 // [reader 0..63][producer 0..63]
    unsigned int* fsub  = fl + NBLK * NBLK;   // [32] (single reader each)
    unsigned int* fexp  = fsub + 32;          // [reader 0..35][expert 0..3]

    __shared__ float s_red[256];
    __shared__ float s_ec[ATOMS];   // sec (P4) / sdec (P5)
    __shared__ float s_sub[SUB_DIM];
    __shared__ int   s_idx[TOPK];
    __shared__ float s_val[TOPK];

    const int b    = blockIdx.x;    // 0..63
    const int t    = threadIdx.x;   // 0..255
    const int lane = t & 63;
    const int wave = t >> 6;

    // ================= P1: codes (4 rows/block, one per wave) =================
    {
        const int c = b * 4 + wave;
        const float* row = enc_top + (size_t)c * INPUT_DIM;
        float acc = 0.0f;
        #pragma unroll
        for (int i = 0; i < INPUT_DIM / 64; ++i)
            acc += row[lane + i * 64] * x[lane + i * 64];
        #pragma unroll
        for (int o = 32; o > 0; o >>= 1) acc += __shfl_down(acc, o);
        if (lane == 0) gstf(&codes[c], (acc >= OFFSET) ? acc : 0.0f);
        __syncthreads();                       // drains each wave's vmcnt (sc1 stores at L3)
        if (t < NBLK) flag_st(&fcode[t * NBLK + b], MAGIC);   // fan-out to all readers
    }

    // ================= P2: every block computes top-4 locally =================
    if (wave == 0) {
        while (!__all(flag_ld(&fcode[b * NBLK + lane]) == MAGIC))
            __builtin_amdgcn_s_sleep(1);
        asm volatile("" ::: "memory");
        flag_st(&fcode[b * NBLK + lane], 0u);  // reader resets own line
        float v[4]; int id[4];
        #pragma unroll
        for (int i = 0; i < 4; ++i) { id[i] = lane + 64 * i; v[i] = gldf(&codes[id[i]]); }
        for (int k = 0; k < TOPK; ++k) {
            float bv = v[0]; int bi = id[0];
            #pragma unroll
            for (int i = 1; i < 4; ++i)
                if (v[i] > bv || (v[i] == bv && id[i] < bi)) { bv = v[i]; bi = id[i]; }
            #pragma unroll
            for (int o = 32; o > 0; o >>= 1) {
                float ov = __shfl_down(bv, o);
                int   oi = __shfl_down(bi, o);
                if (ov > bv || (ov == bv && oi < bi)) { bv = ov; bi = oi; }
            }
            bv = __shfl(bv, 0);
            bi = __shfl(bi, 0);
            if (lane == 0) { s_idx[k] = bi; s_val[k] = bv; }
            #pragma unroll
            for (int i = 0; i < 4; ++i)
                if (id[i] == bi) v[i] = -FLT_MAX;
        }
    }
    __syncthreads();   // publish s_idx/s_val to all waves

    // ================= P3: sub rows (blocks 4..35, 8 rows each) =================
    if (b >= 4 && b < 36) {
        const int j = b - 4;                   // 0..31; expert slot = j>>3
        #pragma unroll
        for (int rr = 0; rr < 2; ++rr) {
            const int r = 8 * j + 2 * wave + rr;       // 0..255
            const int E = s_idx[r >> 6];
            const float* row = W_down + ((size_t)E * SUB_DIM + (r & 63)) * INPUT_DIM;
            float acc = 0.0f;
            #pragma unroll
            for (int i = 0; i < INPUT_DIM / 64; ++i)
                acc += row[lane + i * 64] * x[lane + i * 64];
            #pragma unroll
            for (int o = 32; o > 0; o >>= 1) acc += __shfl_down(acc, o);
            if (lane == 0) gstf(&sub[r], acc);
        }
        __syncthreads();
        if (t == 0) flag_st(&fsub[j], MAGIC);
    }

    // ================= P4: expert encode+decode (blocks 0..3) =================
    if (b < TOPK) {
        const int E = s_idx[b];
        const float* W = enc_w + (size_t)E * ATOMS * SUB_DIM;
        // prefetch enc_w[E] into L2 during the P3 window
        {
            float pf = 0.0f;
            const float4* W4 = (const float4*)W;
            for (int i = t; i < ATOMS * SUB_DIM / 4; i += 256) {
                float4 w = W4[i];
                pf += w.x + w.y + w.z + w.w;
            }
            asm volatile("" :: "v"(pf));
        }
        if (wave == 0) {
            while (!__all(lane < 8 ? (flag_ld(&fsub[8 * b + lane]) == MAGIC) : 1))
                __builtin_amdgcn_s_sleep(1);
            asm volatile("" ::: "memory");
            if (lane < 8) flag_st(&fsub[8 * b + lane], 0u);
            s_sub[lane] = gldf(&sub[b * SUB_DIM + lane]);
        }
        __syncthreads();
        #pragma unroll
        for (int rr = 0; rr < ATOMS / 256; ++rr) {
            int a = t + rr * 256;
            const float4* row4 = (const float4*)(W + (size_t)a * SUB_DIM);
            float acc = 0.0f;
            #pragma unroll
            for (int i = 0; i < SUB_DIM / 4; ++i) {
                float4 w = row4[i];
                acc += w.x * s_sub[4*i] + w.y * s_sub[4*i+1] + w.z * s_sub[4*i+2] + w.w * s_sub[4*i+3];
            }
            s_ec[a] = (acc >= OFFSET) ? acc : 0.01f * acc;   // leaky slope .01
        }
        __syncthreads();
        {
            float acc = 0.0f;
            for (int a = wave * 128; a < (wave + 1) * 128; ++a)
                acc += W[(size_t)a * SUB_DIM + lane] * s_ec[a];
            s_red[t] = acc;
            __syncthreads();
            if (t < SUB_DIM)
                gstf(&dec[b * SUB_DIM + t],
                     s_red[t] + s_red[t + 64] + s_red[t + 128] + s_red[t + 192]);
            __syncthreads();
            if (t < 36) flag_st(&fexp[t * 4 + b], MAGIC);    // fan-out to 36 readers
        }
    }

    // ================= P5: recon (blocks 28..63, preload during P3/P4 window) =================
    if (b >= 28) {
        const int rb = b - 28;                 // 0..35
        const int d  = rb * 64 + lane;
        const int E  = s_idx[wave];            // one expert per wave
        float wr[SUB_DIM];
        const float* Wb = W_down + (size_t)E * SUB_DIM * INPUT_DIM + d;
        #pragma unroll
        for (int s = 0; s < SUB_DIM; ++s) wr[s] = Wb[(size_t)s * INPUT_DIM];
        const float et = s_val[wave] * enc_top[(size_t)E * INPUT_DIM + d];
        if (wave == 0) {
            while (!__all(lane < TOPK ? (flag_ld(&fexp[rb * 4 + lane]) == MAGIC) : 1))
                __builtin_amdgcn_s_sleep(1);
            asm volatile("" ::: "memory");
            if (lane < TOPK) flag_st(&fexp[rb * 4 + lane], 0u);
            #pragma unroll
            for (int k = 0; k < TOPK; ++k)
                s_ec[k * 64 + lane] = gldf(&dec[k * 64 + lane]);
        }
        __syncthreads();
        float acc = et;
        #pragma unroll
        for (int s = 0; s < SUB_DIM; ++s)
            acc += wr[s] * s_ec[wave * 64 + s];
        s_red[t] = acc;
        __syncthreads();
        if (t < 64)
            out[rb * 64 + t] = s_red[t] + s_red[t + 64] + s_red[t + 128] + s_red[t + 192];
    }
}

extern "C" void kernel_launch(void* const* d_in, const int* in_sizes, int n_in,
                              void* d_out, int out_size, void* d_ws, size_t ws_size,
                              hipStream_t stream) {
    const float* x       = (const float*)d_in[0];
    const float* enc_top = (const float*)d_in[1];
    const float* W_down  = (const float*)d_in[2];
    const float* enc_w   = (const float*)d_in[3];
    float* out = (float*)d_out;
    float* ws  = (float*)d_ws;

    moe_fused<<<dim3(NBLK), dim3(256), 0, stream>>>(x, enc_top, W_down, enc_w, out, ws);
}

// Round 6
// 19.930 us; speedup vs baseline: 6.0360x; 1.2068x over previous
//
#include <hip/hip_runtime.h>
#include <float.h>

#define INPUT_DIM 2304
#define SUB_DIM 64
#define ATOMS 512
#define NUM_EXPERTS 256
#define TOPK 4
#define NBLK 128

// offset = 1/sqrt(2304) = 1/48 exactly
#define OFFSET (1.0f / 48.0f)
#define MAGIC 0x9E3779B9u

// ---- fence-free sync: relaxed agent atomics (sc1, coherent at L3) ----
__device__ __forceinline__ unsigned int flag_ld(const unsigned int* p) {
    return __hip_atomic_load(p, __ATOMIC_RELAXED, __HIP_MEMORY_SCOPE_AGENT);
}
__device__ __forceinline__ void flag_st(unsigned int* p, unsigned int v) {
    __hip_atomic_store(p, v, __ATOMIC_RELAXED, __HIP_MEMORY_SCOPE_AGENT);
}
__device__ __forceinline__ float gldf(const float* p) {
    return __hip_atomic_load(p, __ATOMIC_RELAXED, __HIP_MEMORY_SCOPE_AGENT);
}
__device__ __forceinline__ void gstf(float* p, float v) {
    __hip_atomic_store(p, v, __ATOMIC_RELAXED, __HIP_MEMORY_SCOPE_AGENT);
}

// ws floats: codes[256] @0 | sub[256] @256 | dec[256] @512
// flags (u32) @byte 8192: fcode[128][64] | fsub[64] | fexp[36][4]
// MAGIC protocol, single reader resets own flags -> no memset node needed.

__global__ void __launch_bounds__(256, 1) moe_fused(
    const float* __restrict__ x,
    const float* __restrict__ enc_top,
    const float* __restrict__ W_down,
    const float* __restrict__ enc_w,
    float* __restrict__ out,
    float* __restrict__ ws)
{
    float* codes = ws;          // 256
    float* sub   = ws + 256;    // 256
    float* dec   = ws + 512;    // 256
    unsigned int* fl    = (unsigned int*)((char*)ws + 8192);
    unsigned int* fcode = fl;                  // [reader 0..127][producer 0..63]
    unsigned int* fsub  = fl + NBLK * 64;      // [64]
    unsigned int* fexp  = fsub + 64;           // [reader 0..35][expert 0..3]

    __shared__ float s_red[256];
    __shared__ float s_ec[ATOMS];
    __shared__ float s_decp[16][SUB_DIM];      // decode partials [chunk][s]
    __shared__ float s_sub[SUB_DIM];
    __shared__ int   s_idx[TOPK];
    __shared__ float s_val[TOPK];

    const int b    = blockIdx.x;    // 0..127
    const int t    = threadIdx.x;   // 0..255
    const int lane = t & 63;
    const int wave = t >> 6;
    const float4* x4 = (const float4*)x;

    // ================= P1: codes (blocks 0..63, one row per wave, float4) =================
    if (b < 64) {
        const int c = b * 4 + wave;
        const float4* row4 = (const float4*)(enc_top + (size_t)c * INPUT_DIM);
        float acc = 0.0f;
        #pragma unroll
        for (int i = 0; i < INPUT_DIM / 256; ++i) {      // 9 float4 per lane
            float4 w  = row4[lane + 64 * i];
            float4 xv = x4[lane + 64 * i];
            acc += w.x * xv.x + w.y * xv.y + w.z * xv.z + w.w * xv.w;
        }
        #pragma unroll
        for (int o = 32; o > 0; o >>= 1) acc += __shfl_down(acc, o);
        if (lane == 0) gstf(&codes[c], (acc >= OFFSET) ? acc : 0.0f);
        __syncthreads();                // drains vmcnt: codes at L3 before flags
        if (t < NBLK) flag_st(&fcode[t * 64 + b], MAGIC);
    }

    if (b >= 40 && b < 64) return;      // P1-only blocks

    // ================= P2: local top-4 (every remaining block) =================
    if (wave == 0) {
        while (!__all(flag_ld(&fcode[b * 64 + lane]) == MAGIC)) {}
        asm volatile("" ::: "memory");
        flag_st(&fcode[b * 64 + lane], 0u);     // reader resets own line
        float v[4]; int id[4];
        #pragma unroll
        for (int i = 0; i < 4; ++i) { id[i] = lane + 64 * i; v[i] = gldf(&codes[id[i]]); }
        for (int k = 0; k < TOPK; ++k) {
            float bv = v[0]; int bi = id[0];
            #pragma unroll
            for (int i = 1; i < 4; ++i)
                if (v[i] > bv || (v[i] == bv && id[i] < bi)) { bv = v[i]; bi = id[i]; }
            #pragma unroll
            for (int o = 32; o > 0; o >>= 1) {
                float ov = __shfl_down(bv, o);
                int   oi = __shfl_down(bi, o);
                if (ov > bv || (ov == bv && oi < bi)) { bv = ov; bi = oi; }
            }
            bv = __shfl(bv, 0);
            bi = __shfl(bi, 0);
            if (lane == 0) { s_idx[k] = bi; s_val[k] = bv; }
            #pragma unroll
            for (int i = 0; i < 4; ++i)
                if (id[i] == bi) v[i] = -FLT_MAX;
        }
    }
    __syncthreads();

    // ================= P3: sub rows (blocks 64..127, one row per wave) =================
    if (b >= 64) {
        const int r = (b - 64) * 4 + wave;      // 0..255
        const int E = s_idx[r >> 6];
        const float4* row4 = (const float4*)(W_down + ((size_t)E * SUB_DIM + (r & 63)) * INPUT_DIM);
        float acc = 0.0f;
        #pragma unroll
        for (int i = 0; i < INPUT_DIM / 256; ++i) {
            float4 w  = row4[lane + 64 * i];
            float4 xv = x4[lane + 64 * i];
            acc += w.x * xv.x + w.y * xv.y + w.z * xv.z + w.w * xv.w;
        }
        #pragma unroll
        for (int o = 32; o > 0; o >>= 1) acc += __shfl_down(acc, o);
        if (lane == 0) gstf(&sub[r], acc);
        __syncthreads();
        if (t == 0) flag_st(&fsub[b - 64], MAGIC);
        return;
    }

    // ================= P4: expert encode+decode (blocks 0..3) =================
    if (b < TOPK) {
        const int E = s_idx[b];
        const float* W = enc_w + (size_t)E * ATOMS * SUB_DIM;
        // prefetch into L2: one float4 per 64B line (2048 lines / 256 threads = 8 each)
        float pf = 0.0f;
        #pragma unroll
        for (int i = 0; i < 8; ++i) {
            float4 w = ((const float4*)W)[(size_t)(t + i * 256) * 4];
            pf += w.x + w.y + w.z + w.w;
        }
        if (wave == 0) {
            while (!__all(lane < 16 ? (flag_ld(&fsub[b * 16 + lane]) == MAGIC) : 1)) {}
            asm volatile("" ::: "memory");
            if (lane < 16) flag_st(&fsub[b * 16 + lane], 0u);
            s_sub[lane] = gldf(&sub[b * SUB_DIM + lane]);
        }
        asm volatile("" :: "v"(pf));   // keep prefetch alive
        __syncthreads();
        // encode: 2 atoms per thread
        #pragma unroll
        for (int rr = 0; rr < ATOMS / 256; ++rr) {
            int a = t + rr * 256;
            const float4* row4 = (const float4*)(W + (size_t)a * SUB_DIM);
            float acc = 0.0f;
            #pragma unroll
            for (int i = 0; i < SUB_DIM / 4; ++i) {
                float4 w = row4[i];
                acc += w.x * s_sub[4*i] + w.y * s_sub[4*i+1] + w.z * s_sub[4*i+2] + w.w * s_sub[4*i+3];
            }
            s_ec[a] = (acc >= OFFSET) ? acc : 0.01f * acc;   // leaky slope .01
        }
        __syncthreads();
        // decode, tiled: thread (chunk=t>>4, sgroup=t&15) covers 32 atoms x 4 s-cols
        {
            const int sg = t & 15, ch = t >> 4;
            float4 a4 = make_float4(0.f, 0.f, 0.f, 0.f);
            for (int a = ch * 32; a < ch * 32 + 32; ++a) {
                float4 w = *(const float4*)(W + (size_t)a * SUB_DIM + sg * 4);
                float  e = s_ec[a];
                a4.x += w.x * e; a4.y += w.y * e; a4.z += w.z * e; a4.w += w.w * e;
            }
            *(float4*)&s_decp[ch][sg * 4] = a4;
        }
        __syncthreads();
        if (t < SUB_DIM) {
            float d = 0.0f;
            #pragma unroll
            for (int c = 0; c < 16; ++c) d += s_decp[c][t];
            gstf(&dec[b * SUB_DIM + t], d);
        }
        __syncthreads();
        if (t < 36) flag_st(&fexp[t * 4 + b], MAGIC);
        return;
    }

    // ================= P5: recon (blocks 4..39), preload during P3/P4 window =================
    {
        const int rb = b - 4;                  // 0..35
        const int d  = rb * 64 + lane;
        const int E  = s_idx[wave];            // one expert per wave
        float wr[SUB_DIM];
        const float* Wb = W_down + (size_t)E * SUB_DIM * INPUT_DIM + d;
        #pragma unroll
        for (int s = 0; s < SUB_DIM; ++s) wr[s] = Wb[(size_t)s * INPUT_DIM];
        const float et = s_val[wave] * enc_top[(size_t)E * INPUT_DIM + d];
        if (wave == 0) {
            while (!__all(lane < TOPK ? (flag_ld(&fexp[rb * 4 + lane]) == MAGIC) : 1)) {}
            asm volatile("" ::: "memory");
            if (lane < TOPK) flag_st(&fexp[rb * 4 + lane], 0u);
        }
        __syncthreads();
        float dv = gldf(&dec[wave * SUB_DIM + lane]);  // lane l holds dec[e=wave][l]
        float acc = et;
        #pragma unroll
        for (int s = 0; s < SUB_DIM; ++s)
            acc += wr[s] * __shfl(dv, s);
        s_red[t] = acc;
        __syncthreads();
        if (t < 64)
            out[rb * 64 + t] = s_red[t] + s_red[t + 64] + s_red[t + 128] + s_red[t + 192];
    }
}

extern "C" void kernel_launch(void* const* d_in, const int* in_sizes, int n_in,
                              void* d_out, int out_size, void* d_ws, size_t ws_size,
                              hipStream_t stream) {
    const float* x       = (const float*)d_in[0];
    const float* enc_top = (const float*)d_in[1];
    const float* W_down  = (const float*)d_in[2];
    const float* enc_w   = (const float*)d_in[3];
    float* out = (float*)d_out;
    float* ws  = (float*)d_ws;

    moe_fused<<<dim3(NBLK), dim3(256), 0, stream>>>(x, enc_top, W_down, enc_w, out, ws);
}